// Round 7
// baseline (254.462 us; speedup 1.0000x reference)
//
#include <hip/hip_runtime.h>

typedef unsigned short u16;
using bf16x8 = __attribute__((ext_vector_type(8))) short;
using f32x4  = __attribute__((ext_vector_type(4))) float;
using s16x4  = __attribute__((ext_vector_type(4))) short;

#define S_LEN 512
#define D_DIM 128
#define CB    32                     // kv chunk staged in LDS (single-buffered)
#define KS    136                    // K LDS row stride (shorts): conflict-free b128
#define VS    36                     // VT LDS row stride (shorts): 72B rows
#define KBUF  (CB * KS)              // 4352 shorts
#define VBUF  (D_DIM * VS)           // 4608 shorts
#define OWS   68                     // epilogue bounce row stride (floats)
#define SCALE 0.08838834764831845f   // 1/sqrt(128)

// RNE f32 pair -> packed bf16x2 (1 instr, same rounding as round-trip f2b)
__device__ __forceinline__ unsigned int cvt_pk_bf16(float lo, float hi) {
  unsigned int r;
  asm("v_cvt_pk_bf16_f32 %0, %1, %2" : "=v"(r) : "v"(lo), "v"(hi));
  return r;
}
__device__ __forceinline__ bf16x8 pack8(f32x4 a, f32x4 b) {
  union { unsigned int u[4]; bf16x8 v; } r;
  r.u[0] = cvt_pk_bf16(a[0], a[1]);
  r.u[1] = cvt_pk_bf16(a[2], a[3]);
  r.u[2] = cvt_pk_bf16(b[0], b[1]);
  r.u[3] = cvt_pk_bf16(b[2], b[3]);
  return r.v;
}

// fp32 in / fp32 out. S^T = K.Q^T (A=K from LDS, B=Q regs); PV with pi-permuted
// packing. ROUND 7: occupancy play. Single-buffered K/V LDS (17.9 KB/block,
// was 35.8) -> LDS cap 8 blocks/CU, VGPR cap ~6; round-4 measured only 2
// resident blocks and every pipe <25% busy => TLP-starved. 2 barriers/chunk
// (plain __syncthreads(), known-correct; round 6's relaxed raw-barrier
// ordering RACED) with a 1-deep register prefetch so the next chunk's global
// loads overlap this chunk's compute. Epilogue bounces O through the (freed)
// staging LDS in two d-halves per wave for coalesced 256B row stores.
__global__ __launch_bounds__(256, 4)
void attn_fused(const float* __restrict__ Q, const float* __restrict__ K,
                const float* __restrict__ V, const int* __restrict__ VL,
                const float* __restrict__ WM, float* __restrict__ O) {
  __shared__ short smem[KBUF + VBUF];   // 8960 shorts = 17920 B

  const int bid  = blockIdx.x;
  const int n    = (bid & 7) | ((bid >> 6) << 3);   // n%8 == bid%8 (XCD)
  const int qt   = (bid >> 3) & 7;
  const int tid  = threadIdx.x;
  const int wave = tid >> 6;
  const int L    = tid & 63;
  const int quad = L >> 4;
  const int lq   = L & 15;
  const int qw   = qt * 64 + wave * 16;   // wave's q base
  const int qg   = qw + lq;               // this lane's q row
  const int w    = (n >> 3) & 15;         // window index

  short* Ksh = smem;                // [CB][KS]
  short* VTs = smem + KBUF;         // [D_DIM][VS]

  const float* Qn  = Q + (size_t)n * S_LEN * D_DIM;
  const float* Kn  = K + (size_t)n * S_LEN * D_DIM;
  const float* Vn  = V + (size_t)n * S_LEN * D_DIM;
  const float* WMq = WM + ((size_t)w * S_LEN + qg) * S_LEN;

  const int vlen  = VL[n];
  const int kvlim = (vlen == 0) ? S_LEN : vlen;
  const int nch   = (kvlim + CB - 1) / CB;          // 1..16 chunks (block-uniform)
  const int nchm1 = nch - 1;

  // Q fragments (B-operand): lane holds Q[qg][dc*32 + quad*8 + j], j=0..7
  bf16x8 qf[4];
#pragma unroll
  for (int dc = 0; dc < 4; ++dc) {
    const f32x4* qp = (const f32x4*)(Qn + (size_t)qg * D_DIM + dc * 32 + quad * 8);
    qf[dc] = pack8(qp[0], qp[1]);
  }

  f32x4 o[8];
#pragma unroll
  for (int t = 0; t < 8; ++t) o[t] = (f32x4){0.f, 0.f, 0.f, 0.f};
  float mrun = -1e30f, lrun = 0.f;

  // staging geometry: thread covers rows tr and tr+16 of the chunk at d-chunk cc
  const int tr = tid >> 4;          // 0..15
  const int cc = tid & 15;          // 8-float d-chunk
  const int colsw = (cc & 7) << 2;  // VT swizzle key (cc == d>>3)
  const float* Kst = Kn + (size_t)tr * D_DIM + cc * 8;
  const float* Vst = Vn + (size_t)tr * D_DIM + cc * 8;

  // single named register payload (rule #20: no arrays, no conditional writes)
  f32x4 Ak0a, Ak0b, Ak1a, Ak1b, Av0a, Av0b, Av1a, Av1b;

#define STAGE_ISSUE(cb_) {                                              \
    const float* kp0 = Kst + (size_t)(cb_) * D_DIM;                     \
    const float* kp1 = kp0 + 16 * D_DIM;                                \
    const float* vp0 = Vst + (size_t)(cb_) * D_DIM;                     \
    const float* vp1 = vp0 + 16 * D_DIM;                                \
    Ak0a = ((const f32x4*)kp0)[0]; Ak0b = ((const f32x4*)kp0)[1];       \
    Ak1a = ((const f32x4*)kp1)[0]; Ak1b = ((const f32x4*)kp1)[1];       \
    Av0a = ((const f32x4*)vp0)[0]; Av0b = ((const f32x4*)vp0)[1];       \
    Av1a = ((const f32x4*)vp1)[0]; Av1b = ((const f32x4*)vp1)[1]; }

#define STAGE_WRITE() {                                                 \
    *(bf16x8*)(Ksh + tr * KS + cc * 8)        = pack8(Ak0a, Ak0b);      \
    *(bf16x8*)(Ksh + (16 + tr) * KS + cc * 8) = pack8(Ak1a, Ak1b);      \
    short* vt0 = VTs + (cc * 8) * VS + (tr ^ colsw);                    \
    short* vt1 = VTs + (cc * 8) * VS + ((16 + tr) ^ colsw);             \
    unsigned int wa0 = cvt_pk_bf16(Av0a[0], Av0a[1]);                   \
    unsigned int wa1 = cvt_pk_bf16(Av0a[2], Av0a[3]);                   \
    unsigned int wa2 = cvt_pk_bf16(Av0b[0], Av0b[1]);                   \
    unsigned int wa3 = cvt_pk_bf16(Av0b[2], Av0b[3]);                   \
    vt0[0 * VS] = (short)(wa0);  vt0[1 * VS] = (short)(wa0 >> 16);      \
    vt0[2 * VS] = (short)(wa1);  vt0[3 * VS] = (short)(wa1 >> 16);      \
    vt0[4 * VS] = (short)(wa2);  vt0[5 * VS] = (short)(wa2 >> 16);      \
    vt0[6 * VS] = (short)(wa3);  vt0[7 * VS] = (short)(wa3 >> 16);      \
    unsigned int wb0 = cvt_pk_bf16(Av1a[0], Av1a[1]);                   \
    unsigned int wb1 = cvt_pk_bf16(Av1a[2], Av1a[3]);                   \
    unsigned int wb2 = cvt_pk_bf16(Av1b[0], Av1b[1]);                   \
    unsigned int wb3 = cvt_pk_bf16(Av1b[2], Av1b[3]);                   \
    vt1[0 * VS] = (short)(wb0);  vt1[1 * VS] = (short)(wb0 >> 16);      \
    vt1[2 * VS] = (short)(wb1);  vt1[3 * VS] = (short)(wb1 >> 16);      \
    vt1[4 * VS] = (short)(wb2);  vt1[5 * VS] = (short)(wb2 >> 16);      \
    vt1[6 * VS] = (short)(wb3);  vt1[7 * VS] = (short)(wb3 >> 16); }

  auto compute_chunk = [&](int cb) {
    // WM rows for this chunk: issued first, consumed after the QK^T MFMA chain
    f32x4 wm0 = *(const f32x4*)(WMq + cb + quad * 4);
    f32x4 wm1 = *(const f32x4*)(WMq + cb + 16 + quad * 4);

    // ---- S^T: two 16-kv subtiles, A = K rows from LDS, B = Q frags ----
    f32x4 a0 = {0, 0, 0, 0}, a1 = {0, 0, 0, 0};
#pragma unroll
    for (int dc = 0; dc < 4; ++dc) {
      bf16x8 kf0 = *(const bf16x8*)(Ksh + lq * KS + dc * 32 + quad * 8);
      bf16x8 kf1 = *(const bf16x8*)(Ksh + (16 + lq) * KS + dc * 32 + quad * 8);
      a0 = __builtin_amdgcn_mfma_f32_16x16x32_bf16(kf0, qf[dc], a0, 0, 0, 0);
      a1 = __builtin_amdgcn_mfma_f32_16x16x32_bf16(kf1, qf[dc], a1, 0, 0, 0);
    }
    // ---- scores: scale + window mask + valid-len mask (-1e6 like ref) ----
    float s0[4], s1[4];
    float mloc = -1e30f;
#pragma unroll
    for (int r = 0; r < 4; ++r) {
      int k0i = cb + quad * 4 + r;
      s0[r] = (k0i < vlen)      ? a0[r] * SCALE + wm0[r] : -1e6f;
      s1[r] = (k0i + 16 < vlen) ? a1[r] * SCALE + wm1[r] : -1e6f;
      mloc = fmaxf(mloc, fmaxf(s0[r], s1[r]));
    }
    mloc = fmaxf(mloc, __shfl_xor(mloc, 16, 64));
    mloc = fmaxf(mloc, __shfl_xor(mloc, 32, 64));
    const float mnew  = fmaxf(mrun, mloc);
    const float alpha = __expf(mrun - mnew);
    mrun = mnew;

    float ev[8];
#pragma unroll
    for (int r = 0; r < 4; ++r) {
      ev[r]     = __expf(s0[r] - mnew);
      ev[4 + r] = __expf(s1[r] - mnew);
    }
    union { unsigned int u[4]; bf16x8 v; } pfu;
    pfu.u[0] = cvt_pk_bf16(ev[0], ev[1]);
    pfu.u[1] = cvt_pk_bf16(ev[2], ev[3]);
    pfu.u[2] = cvt_pk_bf16(ev[4], ev[5]);
    pfu.u[3] = cvt_pk_bf16(ev[6], ev[7]);
    float psum = 0.f;
#pragma unroll
    for (int t2 = 0; t2 < 4; ++t2) {    // sum the ROUNDED values (consistency)
      union { unsigned int i; float f; } lo, hi;
      lo.i = pfu.u[t2] << 16;
      hi.i = pfu.u[t2] & 0xffff0000u;
      psum += lo.f + hi.f;
    }
    psum += __shfl_xor(psum, 16, 64);
    psum += __shfl_xor(psum, 32, 64);
    lrun = lrun * alpha + psum;

    // alpha for O rows (O C-layout row = quad*4+reg; state lives at lane lq==row)
    float ar[4];
#pragma unroll
    for (int r = 0; r < 4; ++r) ar[r] = __shfl(alpha, quad * 4 + r, 64);

    const bf16x8 pf = pfu.v;   // [T0 p0..p3 | T1 p0..p3] == pi-permuted k order
#pragma unroll
    for (int t = 0; t < 8; ++t) {
      int d   = 16 * t + lq;
      int swz = ((d >> 3) & 7) << 2;
      s16x4 b0 = *(const s16x4*)(VTs + d * VS + ((quad * 4) ^ swz));
      s16x4 b1 = *(const s16x4*)(VTs + d * VS + ((16 + quad * 4) ^ swz));
      bf16x8 bv = {b0[0], b0[1], b0[2], b0[3], b1[0], b1[1], b1[2], b1[3]};
      f32x4 ot = o[t];
#pragma unroll
      for (int r = 0; r < 4; ++r) ot[r] *= ar[r];
      o[t] = __builtin_amdgcn_mfma_f32_16x16x32_bf16(pf, bv, ot, 0, 0, 0);
    }
  };

  // ---- prologue: stage chunk 0 ----
  STAGE_ISSUE(0);
  STAGE_WRITE();                    // compiler inserts the vmcnt wait
  __syncthreads();

  // ---- main loop: issue c+1 loads -> compute c -> barrier -> write -> barrier
  for (int ci = 0;;) {
    const int cpre = (ci + 1 <= nchm1 ? ci + 1 : nchm1) * CB;
    STAGE_ISSUE(cpre);              // overlaps the whole compute phase
    compute_chunk(ci * CB);
    if (++ci >= nch) break;
    __syncthreads();                // all readers done with the buffer
    STAGE_WRITE();                  // write chunk ci
    __syncthreads();                // data ready
  }
  __syncthreads();                  // staging LDS free for epilogue reuse

  // ---- epilogue: normalize; bounce O through LDS per wave in two d-halves ----
  float linv[4];
#pragma unroll
  for (int r = 0; r < 4; ++r) {
    float lr = __shfl(lrun, quad * 4 + r, 64);
    linv[r] = 1.f / lr;
  }
  float* ow = (float*)smem + wave * (16 * OWS);   // 16 rows x 68 floats / wave
  float* On = O + (size_t)n * S_LEN * D_DIM;
  const int row = L >> 2;           // 16 rows, 4 lanes each
  const int cb4 = (L & 3) * 16;     // 64-float half-row in 16-float strips
#pragma unroll
  for (int h = 0; h < 2; ++h) {
    // write this wave's half (d = 64h .. 64h+63); private region, no barrier:
    // compiler orders the intra-wave LDS write->read / read->overwrite deps.
#pragma unroll
    for (int tt = 0; tt < 4; ++tt) {
      const int t = h * 4 + tt;
#pragma unroll
      for (int r = 0; r < 4; ++r)
        ow[(quad * 4 + r) * OWS + tt * 16 + lq] = o[t][r] * linv[r];
    }
#pragma unroll
    for (int j = 0; j < 4; ++j) {
      f32x4 v = *(const f32x4*)(ow + row * OWS + cb4 + 4 * j);
      *(f32x4*)(On + (size_t)(qw + row) * D_DIM + h * 64 + cb4 + 4 * j) = v;
    }
  }
}

extern "C" void kernel_launch(void* const* d_in, const int* in_sizes, int n_in,
                              void* d_out, int out_size, void* d_ws, size_t ws_size,
                              hipStream_t stream) {
  const float* Q  = (const float*)d_in[0];
  const float* K  = (const float*)d_in[1];
  const float* V  = (const float*)d_in[2];
  const int*   VL = (const int*)d_in[3];
  const float* WM = (const float*)d_in[4];
  float* O = (float*)d_out;
  dim3 grid(256 * 8), block(256);
  attn_fused<<<grid, block, 0, stream>>>(Q, K, V, VL, WM, O);
}